// Round 10
// baseline (646.576 us; speedup 1.0000x reference)
//
#include <hip/hip_runtime.h>
#include <math.h>

typedef unsigned short ushort_t;
typedef __attribute__((ext_vector_type(8))) __bf16 bf16x8;
typedef __attribute__((ext_vector_type(4))) float floatx4;

#define B_    256
#define I_    1152
#define J_    10
#define DIN_  8
#define DOUT_ 16
#define K_    (I_*DIN_)     // 9216
#define N_    (J_*DOUT_)    // 160
#define NSPLIT 32
#define KCHUNK (K_/NSPLIT)  // 288 (36 i's per split)
#define KSTEPS (KCHUNK/32)  // 9
#define SR_BLOCKS 1280
#define NGROUP 40           // tile-groups: group g = 32 blocks covering tiles 4g..4g+3

static __device__ __forceinline__ ushort_t f2bf(float f) {
    unsigned int u = __float_as_uint(f);
    u += 0x7fffu + ((u >> 16) & 1u);     // RNE
    return (ushort_t)(u >> 16);
}
static __device__ __forceinline__ float bf2f(ushort_t h) {
    return __uint_as_float(((unsigned int)h) << 16);
}

// ---------------------------------------------------------------------------
// Fused s-GEMM + split-K reduce + squash. S = X @ (c o W)^T, M=256 N=160
// K=9216 split 32 ways; fp32-equivalent via Dekker hi/lo splits (3 MFMAs).
// Split-K reduction via per-group arrival counters (last block reduces);
// one release fence per block, acquire fence only in the 40 reducer blocks —
// NOT a grid barrier (round-8's repeated invalidation was the disaster).
// iter==0: c = 0.1f exactly (softmax of zero logits) — blog never read.
// iter==0 also appends the Xt hi/lo transpose prep (first consumed next
// dispatch, so only dispatch-boundary ordering is needed).
// ---------------------------------------------------------------------------
__global__ __launch_bounds__(256)
void gemm_sr_kernel(const float* __restrict__ x, const float* __restrict__ W,
                    const float* __restrict__ blog, float* __restrict__ P,
                    float* __restrict__ s_out,
                    ushort_t* __restrict__ Sbt_hi, ushort_t* __restrict__ Sbt_lo,
                    unsigned* __restrict__ cnt, const int iter,
                    ushort_t* __restrict__ Xt_hi, ushort_t* __restrict__ Xt_lo)
{
    const int tid  = threadIdx.x;
    const int blk  = blockIdx.x;          // 0..1279
    const int lane = tid & 63;
    const int ks   = blk / NGROUP;        // 0..31 (uniform per block)
    const int g    = blk % NGROUP;        // tile-group

    __shared__ float c_lds[36 * J_];
    __shared__ int   is_last;

    if (iter > 0) {
        // softmax for rows i = ks*36 .. +35
        if (tid < 36) {
            const float* br = blog + (size_t)(ks * 36 + tid) * J_;
            float bv[J_];
            float mx = -1e30f;
            #pragma unroll
            for (int j = 0; j < J_; ++j) { bv[j] = br[j]; mx = fmaxf(mx, bv[j]); }
            float sum = 0.f;
            #pragma unroll
            for (int j = 0; j < J_; ++j) { bv[j] = __expf(bv[j] - mx); sum += bv[j]; }
            float inv = 1.f / sum;
            #pragma unroll
            for (int j = 0; j < J_; ++j) c_lds[tid * J_ + j] = bv[j] * inv;
        }
        __syncthreads();
    }

    // ---- main GEMM: wave tile ----
    {
        const int wv   = blk * 4 + (tid >> 6);
        const int tile = wv % 160;            // = 4g + waveid
        const int mb = tile / J_, nt = tile % J_;
        const int r = lane & 15, q = lane >> 4;
        const float* ap = x + (size_t)(mb * 16 + r) * K_ + ks * KCHUNK + 8 * q;
        const float* wp = W + (((size_t)(ks * 36 + q) * J_ + nt) * DOUT_ + r) * DIN_;
        floatx4 acc = {0.f, 0.f, 0.f, 0.f};
        #pragma unroll
        for (int s = 0; s < KSTEPS; ++s) {
            float4 xa0 = *(const float4*)(ap + s * 32);
            float4 xa1 = *(const float4*)(ap + s * 32 + 4);
            float4 w0  = *(const float4*)(wp + (size_t)s * 4 * J_ * DOUT_ * DIN_);
            float4 w1  = *(const float4*)(wp + (size_t)s * 4 * J_ * DOUT_ * DIN_ + 4);
            float cs   = (iter == 0) ? 0.1f : c_lds[(4 * s + q) * J_ + nt];
            float xv[8]  = {xa0.x, xa0.y, xa0.z, xa0.w, xa1.x, xa1.y, xa1.z, xa1.w};
            float wvv[8] = {w0.x, w0.y, w0.z, w0.w, w1.x, w1.y, w1.z, w1.w};
            bf16x8 ah, al, bh, bl;
            #pragma unroll
            for (int e = 0; e < 8; ++e) {
                float xe = xv[e];
                __bf16 h = (__bf16)xe;
                ah[e] = h;
                al[e] = (__bf16)(xe - (float)h);
                float pe = wvv[e] * cs;
                __bf16 gg = (__bf16)pe;
                bh[e] = gg;
                bl[e] = (__bf16)(pe - (float)gg);
            }
            acc = __builtin_amdgcn_mfma_f32_16x16x32_bf16(ah, bh, acc, 0, 0, 0);
            acc = __builtin_amdgcn_mfma_f32_16x16x32_bf16(al, bh, acc, 0, 0, 0);
            acc = __builtin_amdgcn_mfma_f32_16x16x32_bf16(ah, bl, acc, 0, 0, 0);
        }
        ((floatx4*)P)[(size_t)(ks * 160 + tile) * 64 + lane] = acc;
    }

    // ---- arrive: publish P, bump group counter; last block reduces ----
    __builtin_amdgcn_fence(__ATOMIC_RELEASE, "agent");   // all threads: drain + wb
    __syncthreads();
    if (tid == 0) {
        unsigned old = __hip_atomic_fetch_add(&cnt[g], 1u, __ATOMIC_ACQ_REL,
                                              __HIP_MEMORY_SCOPE_AGENT);
        is_last = (old == NSPLIT - 1);
    }
    __syncthreads();

    if (is_last) {
        __builtin_amdgcn_fence(__ATOMIC_ACQUIRE, "agent");   // invalidate stale lines
        const int b_local = tid >> 4;     // 0..15
        const int o       = tid & 15;     // 0..15 (d in consecutive lanes)
        const int lane_c  = ((b_local >> 2) << 4) | o;   // C/D: col=lane&15, row=quad*4+reg
        const int reg     = b_local & 3;
        #pragma unroll
        for (int u = 0; u < 4; ++u) {
            const int tile = 4 * g + u;
            const int mb = tile / J_, nt = tile % J_;
            const int b  = mb * 16 + b_local;
            const int jo = nt * 16 + o;
            float v = 0.f;
            #pragma unroll
            for (int k2 = 0; k2 < NSPLIT; ++k2)
                v += P[((size_t)(k2 * 160 + tile) * 64 + lane_c) * 4 + reg];
            float sq = v * v;
            #pragma unroll
            for (int off = 1; off < 16; off <<= 1)
                sq += __shfl_xor(sq, off, 16);
            float l2 = sqrtf(sq);
            float val = v * (l2 / (1.f + sq));
            s_out[(size_t)b * N_ + jo] = val;
            ushort_t hi = f2bf(val);
            Sbt_hi[(size_t)jo * B_ + b] = hi;
            Sbt_lo[(size_t)jo * B_ + b] = f2bf(val - bf2f(hi));
        }
        if (tid == 0)   // reset for the next sr dispatch (ordered by dispatch boundary)
            __hip_atomic_store(&cnt[g], 0u, __ATOMIC_RELAXED, __HIP_MEMORY_SCOPE_AGENT);
    }

    // ---- iter==0 tail: Xt hi/lo transpose prep (consumed next dispatch) ----
    if (iter == 0) {
        for (int t = blk * 256 + tid; t < B_ * K_ / 4; t += SR_BLOCKS * 256) {
            int k  = t >> 6;
            int b0 = (t & 63) * 4;
            ushort4 hi, lo;
            float v;
            v = x[(size_t)(b0 + 0) * K_ + k]; hi.x = f2bf(v); lo.x = f2bf(v - bf2f(hi.x));
            v = x[(size_t)(b0 + 1) * K_ + k]; hi.y = f2bf(v); lo.y = f2bf(v - bf2f(hi.y));
            v = x[(size_t)(b0 + 2) * K_ + k]; hi.z = f2bf(v); lo.z = f2bf(v - bf2f(hi.z));
            v = x[(size_t)(b0 + 3) * K_ + k]; hi.w = f2bf(v); lo.w = f2bf(v - bf2f(hi.w));
            ((ushort4*)Xt_hi)[(size_t)k * 64 + (t & 63)] = hi;
            ((ushort4*)Xt_lo)[(size_t)k * 64 + (t & 63)] = lo;
        }
    }
}

// ---------------------------------------------------------------------------
// b-update GEMM: T2 = Xt @ S' (M=9216 N=160 K=256), hi/lo split both sides,
// contracted with fp32 W in-register. Unique (i,j) writer per half-wave.
// first!=0: blog = val (replaces zero-init + accumulate).
// ---------------------------------------------------------------------------
__global__ __launch_bounds__(256)
void gemm_bupd_kernel(const ushort_t* __restrict__ Xt_hi, const ushort_t* __restrict__ Xt_lo,
                      const ushort_t* __restrict__ Sbt_hi, const ushort_t* __restrict__ Sbt_lo,
                      const float* __restrict__ W, float* __restrict__ blog,
                      const int first)
{
    int wv   = blockIdx.x * 4 + (threadIdx.x >> 6);   // 0..5759
    int lane = threadIdx.x & 63;
    int mt = wv / J_;                                 // 0..575
    int j  = wv - mt * J_;
    int r = lane & 15, q = lane >> 4;
    size_t aoff = (size_t)(mt * 16 + r) * B_ + 8 * q;
    size_t boff = (size_t)(j * 16 + r) * B_ + 8 * q;
    floatx4 acc = {0.f, 0.f, 0.f, 0.f};
    #pragma unroll
    for (int s = 0; s < B_ / 32; ++s) {
        bf16x8 ah = *(const bf16x8*)(Xt_hi + aoff + s * 32);
        bf16x8 al = *(const bf16x8*)(Xt_lo + aoff + s * 32);
        bf16x8 bh = *(const bf16x8*)(Sbt_hi + boff + s * 32);
        bf16x8 bl = *(const bf16x8*)(Sbt_lo + boff + s * 32);
        acc = __builtin_amdgcn_mfma_f32_16x16x32_bf16(ah, bh, acc, 0, 0, 0);
        acc = __builtin_amdgcn_mfma_f32_16x16x32_bf16(al, bh, acc, 0, 0, 0);
        acc = __builtin_amdgcn_mfma_f32_16x16x32_bf16(ah, bl, acc, 0, 0, 0);
    }
    // rows q*4+reg -> i = mt*2 + (q>>1), d = (q&1)*4 + reg; col -> o = lane&15
    int i  = mt * 2 + (q >> 1);
    int d0 = (q & 1) * 4;
    int o  = lane & 15;
    const float4 w4 = *(const float4*)(W + ((((size_t)i * J_ + j) * DOUT_ + o) * DIN_ + d0));
    float val = acc[0] * w4.x + acc[1] * w4.y + acc[2] * w4.z + acc[3] * w4.w;
    #pragma unroll
    for (int off = 1; off < 32; off <<= 1)
        val += __shfl_xor(val, off, 32);
    if ((lane & 31) == 0) {
        float* dst = blog + (size_t)(mt * 2 + (lane >> 5)) * J_ + j;
        if (first) *dst = val; else *dst += val;      // unique writer
    }
}

// ---------------------------------------------------------------------------
extern "C" void kernel_launch(void* const* d_in, const int* in_sizes, int n_in,
                              void* d_out, int out_size, void* d_ws, size_t ws_size,
                              hipStream_t stream)
{
    const float* x = (const float*)d_in[0];   // [B, I, DIN]
    const float* W = (const float*)d_in[1];   // [I, J, DOUT, DIN]
    float* s_out = (float*)d_out;             // [B, J, DOUT]

    char* ws = (char*)d_ws;
    ushort_t* Xt_hi  = (ushort_t*)(ws);                    //  4,718,592 B
    ushort_t* Xt_lo  = (ushort_t*)(ws + 4718592);          //  4,718,592 B
    ushort_t* Sbt_hi = (ushort_t*)(ws + 9437184);          //     81,920 B
    ushort_t* Sbt_lo = (ushort_t*)(ws + 9519104);          //     81,920 B
    float*    P      = (float*)   (ws + 9601024);          //  5,242,880 B
    float*    blog   = (float*)   (ws + 14843904);         //     46,080 B
    unsigned* cnt    = (unsigned*)(ws + 14889984);         //        160 B

    hipMemsetAsync(cnt, 0, NGROUP * sizeof(unsigned), stream);

    for (int it = 0; it < 3; ++it) {
        gemm_sr_kernel<<<SR_BLOCKS, 256, 0, stream>>>(x, W, blog, P, s_out,
                                                      Sbt_hi, Sbt_lo, cnt, it,
                                                      Xt_hi, Xt_lo);
        if (it < 2)
            gemm_bupd_kernel<<<1440, 256, 0, stream>>>(Xt_hi, Xt_lo, Sbt_hi, Sbt_lo,
                                                       W, blog, it == 0 ? 1 : 0);
    }
}

// Round 11
// 189.811 us; speedup vs baseline: 3.4064x; 3.4064x over previous
//
#include <hip/hip_runtime.h>
#include <math.h>

typedef unsigned short ushort_t;
typedef __attribute__((ext_vector_type(8))) __bf16 bf16x8;
typedef __attribute__((ext_vector_type(4))) float floatx4;

#define B_    256
#define I_    1152
#define J_    10
#define DIN_  8
#define DOUT_ 16
#define K_    (I_*DIN_)     // 9216
#define N_    (J_*DOUT_)    // 160
#define WPS   16            // waves per block = in-block split-K
#define KCHUNK (K_/WPS)     // 576 (72 i's per wave)
#define KSTEPS (KCHUNK/32)  // 18

static __device__ __forceinline__ ushort_t f2bf(float f) {
    unsigned int u = __float_as_uint(f);
    u += 0x7fffu + ((u >> 16) & 1u);     // RNE
    return (ushort_t)(u >> 16);
}
static __device__ __forceinline__ float bf2f(ushort_t h) {
    return __uint_as_float(((unsigned int)h) << 16);
}

// ---------------------------------------------------------------------------
// Fused s-GEMM + split-K reduce + squash — ALL within one workgroup per tile
// (no cross-block sync; __syncthreads only). 160 blocks x 1024 thr (16 waves).
// Wave w handles k-chunk [w*576, (w+1)*576): 18 steps x 3 MFMAs (Dekker hi/lo
// both operands => fp32-equivalent). Partials via 16KB LDS; reduce+squash+Sbt
// emit by the first 256 threads. Softmax block-local (only j = nt needed).
// iter==0: c = 0.1f exactly (softmax of zero logits), blog never read; the
// iter==0 dispatch also appends the Xt hi/lo transpose prep (consumed only by
// the NEXT dispatch -> ordered by the dispatch boundary, no fences).
// ---------------------------------------------------------------------------
__global__ __launch_bounds__(1024)
void gemm_s_fused_kernel(const float* __restrict__ x, const float* __restrict__ W,
                         const float* __restrict__ blog, float* __restrict__ s_out,
                         ushort_t* __restrict__ Sbt_hi, ushort_t* __restrict__ Sbt_lo,
                         const int iter,
                         ushort_t* __restrict__ Xt_hi, ushort_t* __restrict__ Xt_lo)
{
    const int tid  = threadIdx.x;          // 0..1023
    const int tile = blockIdx.x;           // 0..159
    const int lane = tid & 63;
    const int w    = tid >> 6;             // wave = k-split 0..15
    const int mb   = tile / J_;
    const int nt   = tile - mb * J_;

    __shared__ float  c_lds[I_];           // c[i][nt] only: 4.6 KB
    __shared__ floatx4 part[WPS * 64];     // 16 KB partials

    if (iter > 0) {
        for (int r2 = tid; r2 < I_; r2 += 1024) {
            const float* br = blog + (size_t)r2 * J_;
            float bv[J_];
            float mx = -1e30f;
            #pragma unroll
            for (int j = 0; j < J_; ++j) { bv[j] = br[j]; mx = fmaxf(mx, bv[j]); }
            float sum = 0.f;
            #pragma unroll
            for (int j = 0; j < J_; ++j) { bv[j] = __expf(bv[j] - mx); sum += bv[j]; }
            c_lds[r2] = bv[nt] / sum;
        }
        __syncthreads();
    }

    // ---- per-wave GEMM over its k-chunk ----
    {
        const int r = lane & 15, q = lane >> 4;
        const float* ap = x + (size_t)(mb * 16 + r) * K_ + w * KCHUNK + 8 * q;
        // B row (j=nt, o=r); k-frag covers i = w*72 + 4s + q, d=0..7
        const float* wp = W + (((size_t)(w * 72 + q) * J_ + nt) * DOUT_ + r) * DIN_;
        floatx4 acc = {0.f, 0.f, 0.f, 0.f};
        #pragma unroll
        for (int s = 0; s < KSTEPS; ++s) {
            float4 xa0 = *(const float4*)(ap + s * 32);
            float4 xa1 = *(const float4*)(ap + s * 32 + 4);
            float4 w0  = *(const float4*)(wp + (size_t)s * 4 * J_ * DOUT_ * DIN_);
            float4 w1  = *(const float4*)(wp + (size_t)s * 4 * J_ * DOUT_ * DIN_ + 4);
            float cs   = (iter == 0) ? 0.1f : c_lds[w * 72 + 4 * s + q];
            float xv[8]  = {xa0.x, xa0.y, xa0.z, xa0.w, xa1.x, xa1.y, xa1.z, xa1.w};
            float wvv[8] = {w0.x, w0.y, w0.z, w0.w, w1.x, w1.y, w1.z, w1.w};
            bf16x8 ah, al, bh, bl;
            #pragma unroll
            for (int e = 0; e < 8; ++e) {
                float xe = xv[e];
                __bf16 h = (__bf16)xe;
                ah[e] = h;
                al[e] = (__bf16)(xe - (float)h);
                float pe = wvv[e] * cs;
                __bf16 g = (__bf16)pe;
                bh[e] = g;
                bl[e] = (__bf16)(pe - (float)g);
            }
            acc = __builtin_amdgcn_mfma_f32_16x16x32_bf16(ah, bh, acc, 0, 0, 0);
            acc = __builtin_amdgcn_mfma_f32_16x16x32_bf16(al, bh, acc, 0, 0, 0);
            acc = __builtin_amdgcn_mfma_f32_16x16x32_bf16(ah, bl, acc, 0, 0, 0);
        }
        part[w * 64 + lane] = acc;
    }
    __syncthreads();

    // ---- reduce 16 partials + squash + emit (threads 0..255) ----
    if (tid < 256) {
        const int b_local = tid >> 4;                  // 0..15 (M row)
        const int o       = tid & 15;                  // 0..15 (N col)
        const int lane_c  = ((b_local >> 2) << 4) | o; // C/D: col=lane&15, row=quad*4+reg
        const int reg     = b_local & 3;
        float v = 0.f;
        #pragma unroll
        for (int u = 0; u < WPS; ++u)
            v += part[u * 64 + lane_c][reg];
        float sq = v * v;
        #pragma unroll
        for (int off = 1; off < 16; off <<= 1)
            sq += __shfl_xor(sq, off, 16);
        float l2 = sqrtf(sq);
        float val = v * (l2 / (1.f + sq));
        const int b  = mb * 16 + b_local;
        const int jo = nt * 16 + o;
        s_out[(size_t)b * N_ + jo] = val;
        ushort_t hi = f2bf(val);
        Sbt_hi[(size_t)jo * B_ + b] = hi;
        Sbt_lo[(size_t)jo * B_ + b] = f2bf(val - bf2f(hi));
    }

    // ---- iter==0 tail: Xt hi/lo transpose prep (consumed next dispatch) ----
    if (iter == 0) {
        for (int t = tile * 1024 + tid; t < B_ * K_ / 4; t += 160 * 1024) {
            int k  = t >> 6;
            int b0 = (t & 63) * 4;
            ushort4 hi, lo;
            float v;
            v = x[(size_t)(b0 + 0) * K_ + k]; hi.x = f2bf(v); lo.x = f2bf(v - bf2f(hi.x));
            v = x[(size_t)(b0 + 1) * K_ + k]; hi.y = f2bf(v); lo.y = f2bf(v - bf2f(hi.y));
            v = x[(size_t)(b0 + 2) * K_ + k]; hi.z = f2bf(v); lo.z = f2bf(v - bf2f(hi.z));
            v = x[(size_t)(b0 + 3) * K_ + k]; hi.w = f2bf(v); lo.w = f2bf(v - bf2f(hi.w));
            ((ushort4*)Xt_hi)[(size_t)k * 64 + (t & 63)] = hi;
            ((ushort4*)Xt_lo)[(size_t)k * 64 + (t & 63)] = lo;
        }
    }
}

// ---------------------------------------------------------------------------
// b-update GEMM: T2 = Xt @ S' (M=9216 N=160 K=256), hi/lo split both sides,
// contracted with fp32 W in-register. Unique (i,j) writer per half-wave.
// first!=0: blog = val (replaces zero-init + accumulate).
// ---------------------------------------------------------------------------
__global__ __launch_bounds__(256)
void gemm_bupd_kernel(const ushort_t* __restrict__ Xt_hi, const ushort_t* __restrict__ Xt_lo,
                      const ushort_t* __restrict__ Sbt_hi, const ushort_t* __restrict__ Sbt_lo,
                      const float* __restrict__ W, float* __restrict__ blog,
                      const int first)
{
    int wv   = blockIdx.x * 4 + (threadIdx.x >> 6);   // 0..5759
    int lane = threadIdx.x & 63;
    int mt = wv / J_;                                 // 0..575
    int j  = wv - mt * J_;
    int r = lane & 15, q = lane >> 4;
    size_t aoff = (size_t)(mt * 16 + r) * B_ + 8 * q;
    size_t boff = (size_t)(j * 16 + r) * B_ + 8 * q;
    floatx4 acc = {0.f, 0.f, 0.f, 0.f};
    #pragma unroll
    for (int s = 0; s < B_ / 32; ++s) {
        bf16x8 ah = *(const bf16x8*)(Xt_hi + aoff + s * 32);
        bf16x8 al = *(const bf16x8*)(Xt_lo + aoff + s * 32);
        bf16x8 bh = *(const bf16x8*)(Sbt_hi + boff + s * 32);
        bf16x8 bl = *(const bf16x8*)(Sbt_lo + boff + s * 32);
        acc = __builtin_amdgcn_mfma_f32_16x16x32_bf16(ah, bh, acc, 0, 0, 0);
        acc = __builtin_amdgcn_mfma_f32_16x16x32_bf16(al, bh, acc, 0, 0, 0);
        acc = __builtin_amdgcn_mfma_f32_16x16x32_bf16(ah, bl, acc, 0, 0, 0);
    }
    // rows q*4+reg -> i = mt*2 + (q>>1), d = (q&1)*4 + reg; col -> o = lane&15
    int i  = mt * 2 + (q >> 1);
    int d0 = (q & 1) * 4;
    int o  = lane & 15;
    const float4 w4 = *(const float4*)(W + ((((size_t)i * J_ + j) * DOUT_ + o) * DIN_ + d0));
    float val = acc[0] * w4.x + acc[1] * w4.y + acc[2] * w4.z + acc[3] * w4.w;
    #pragma unroll
    for (int off = 1; off < 32; off <<= 1)
        val += __shfl_xor(val, off, 32);
    if ((lane & 31) == 0) {
        float* dst = blog + (size_t)(mt * 2 + (lane >> 5)) * J_ + j;
        if (first) *dst = val; else *dst += val;      // unique writer
    }
}

// ---------------------------------------------------------------------------
extern "C" void kernel_launch(void* const* d_in, const int* in_sizes, int n_in,
                              void* d_out, int out_size, void* d_ws, size_t ws_size,
                              hipStream_t stream)
{
    const float* x = (const float*)d_in[0];   // [B, I, DIN]
    const float* W = (const float*)d_in[1];   // [I, J, DOUT, DIN]
    float* s_out = (float*)d_out;             // [B, J, DOUT]

    char* ws = (char*)d_ws;
    ushort_t* Xt_hi  = (ushort_t*)(ws);                    //  4,718,592 B
    ushort_t* Xt_lo  = (ushort_t*)(ws + 4718592);          //  4,718,592 B
    ushort_t* Sbt_hi = (ushort_t*)(ws + 9437184);          //     81,920 B
    ushort_t* Sbt_lo = (ushort_t*)(ws + 9519104);          //     81,920 B
    float*    blog   = (float*)   (ws + 9601024);          //     46,080 B (~9.6 MB)

    for (int it = 0; it < 3; ++it) {
        gemm_s_fused_kernel<<<160, 1024, 0, stream>>>(x, W, blog, s_out,
                                                      Sbt_hi, Sbt_lo, it,
                                                      Xt_hi, Xt_lo);
        if (it < 2)
            gemm_bupd_kernel<<<1440, 256, 0, stream>>>(Xt_hi, Xt_lo, Sbt_hi, Sbt_lo,
                                                       W, blog, it == 0 ? 1 : 0);
    }
}

// Round 12
// 163.289 us; speedup vs baseline: 3.9597x; 1.1624x over previous
//
#include <hip/hip_runtime.h>
#include <math.h>

typedef unsigned short ushort_t;
typedef __attribute__((ext_vector_type(8))) __bf16 bf16x8;
typedef __attribute__((ext_vector_type(4))) float floatx4;

#define B_    256
#define I_    1152
#define J_    10
#define DIN_  8
#define DOUT_ 16
#define K_    (I_*DIN_)     // 9216
#define N_    (J_*DOUT_)    // 160
#define WPS   16            // waves per block = in-block split-K
#define KCHUNK (K_/WPS)     // 576 (72 i's per wave)
#define KSTEPS (KCHUNK/32)  // 18

static __device__ __forceinline__ ushort_t f2bf(float f) {
    unsigned int u = __float_as_uint(f);
    u += 0x7fffu + ((u >> 16) & 1u);     // RNE
    return (ushort_t)(u >> 16);
}
static __device__ __forceinline__ float bf2f(ushort_t h) {
    return __uint_as_float(((unsigned int)h) << 16);
}

// ---------------------------------------------------------------------------
// Fused s-GEMM + in-block split-K reduce + squash. 160 blocks x 1024 thr
// (16 waves; wave w = k-chunk w). Dekker hi/lo on both operands (3 MFMAs)
// => fp32-equivalent. Partials via LDS; __syncthreads only.
// iter==0: c = 0.1f exactly (softmax of zero logits) — blog never read.
// iter<2: emit Sbt hi/lo (bupd inputs). iter==2: emit s_out only.
// ---------------------------------------------------------------------------
__global__ __launch_bounds__(1024)
void gemm_s_fused_kernel(const float* __restrict__ x, const float* __restrict__ W,
                         const float* __restrict__ blog, float* __restrict__ s_out,
                         ushort_t* __restrict__ Sbt_hi, ushort_t* __restrict__ Sbt_lo,
                         const int iter)
{
    const int tid  = threadIdx.x;          // 0..1023
    const int tile = blockIdx.x;           // 0..159
    const int lane = tid & 63;
    const int w    = tid >> 6;             // wave = k-split 0..15
    const int mb   = tile / J_;
    const int nt   = tile - mb * J_;

    __shared__ float  c_lds[I_];           // c[i][nt] only: 4.6 KB
    __shared__ floatx4 part[WPS * 64];     // 16 KB partials

    if (iter > 0) {
        for (int r2 = tid; r2 < I_; r2 += 1024) {
            const float* br = blog + (size_t)r2 * J_;
            float bv[J_];
            float mx = -1e30f;
            #pragma unroll
            for (int j = 0; j < J_; ++j) { bv[j] = br[j]; mx = fmaxf(mx, bv[j]); }
            float sum = 0.f;
            #pragma unroll
            for (int j = 0; j < J_; ++j) { bv[j] = __expf(bv[j] - mx); sum += bv[j]; }
            c_lds[r2] = bv[nt] / sum;
        }
        __syncthreads();
    }

    // ---- per-wave GEMM over its k-chunk ----
    {
        const int r = lane & 15, q = lane >> 4;
        const float* ap = x + (size_t)(mb * 16 + r) * K_ + w * KCHUNK + 8 * q;
        // B row (j=nt, o=r); k-frag covers i = w*72 + 4s + q, d=0..7
        const float* wp = W + (((size_t)(w * 72 + q) * J_ + nt) * DOUT_ + r) * DIN_;
        floatx4 acc = {0.f, 0.f, 0.f, 0.f};
        #pragma unroll
        for (int s = 0; s < KSTEPS; ++s) {
            float4 xa0 = *(const float4*)(ap + s * 32);
            float4 xa1 = *(const float4*)(ap + s * 32 + 4);
            float4 w0  = *(const float4*)(wp + (size_t)s * 4 * J_ * DOUT_ * DIN_);
            float4 w1  = *(const float4*)(wp + (size_t)s * 4 * J_ * DOUT_ * DIN_ + 4);
            float cs   = (iter == 0) ? 0.1f : c_lds[w * 72 + 4 * s + q];
            float xv[8]  = {xa0.x, xa0.y, xa0.z, xa0.w, xa1.x, xa1.y, xa1.z, xa1.w};
            float wvv[8] = {w0.x, w0.y, w0.z, w0.w, w1.x, w1.y, w1.z, w1.w};
            bf16x8 ah, al, bh, bl;
            #pragma unroll
            for (int e = 0; e < 8; ++e) {
                float xe = xv[e];
                __bf16 h = (__bf16)xe;
                ah[e] = h;
                al[e] = (__bf16)(xe - (float)h);
                float pe = wvv[e] * cs;
                __bf16 g = (__bf16)pe;
                bh[e] = g;
                bl[e] = (__bf16)(pe - (float)g);
            }
            acc = __builtin_amdgcn_mfma_f32_16x16x32_bf16(ah, bh, acc, 0, 0, 0);
            acc = __builtin_amdgcn_mfma_f32_16x16x32_bf16(al, bh, acc, 0, 0, 0);
            acc = __builtin_amdgcn_mfma_f32_16x16x32_bf16(ah, bl, acc, 0, 0, 0);
        }
        part[w * 64 + lane] = acc;
    }
    __syncthreads();

    // ---- reduce 16 partials + squash + emit (threads 0..255) ----
    if (tid < 256) {
        const int b_local = tid >> 4;                  // 0..15 (M row)
        const int o       = tid & 15;                  // 0..15 (N col)
        const int lane_c  = ((b_local >> 2) << 4) | o; // C/D: col=lane&15, row=quad*4+reg
        const int reg     = b_local & 3;
        float v = 0.f;
        #pragma unroll
        for (int u = 0; u < WPS; ++u)
            v += part[u * 64 + lane_c][reg];
        float sq = v * v;
        #pragma unroll
        for (int off = 1; off < 16; off <<= 1)
            sq += __shfl_xor(sq, off, 16);
        float l2 = sqrtf(sq);
        float val = v * (l2 / (1.f + sq));
        const int b  = mb * 16 + b_local;
        const int jo = nt * 16 + o;
        if (iter == 2) {
            s_out[(size_t)b * N_ + jo] = val;
        } else {
            ushort_t hi = f2bf(val);
            Sbt_hi[(size_t)jo * B_ + b] = hi;
            Sbt_lo[(size_t)jo * B_ + b] = f2bf(val - bf2f(hi));
        }
    }
}

// ---------------------------------------------------------------------------
// b-update GEMM: T2 = X^T @ S' (M=9216 N=160 K=256). A-fragments read DIRECTLY
// from fp32 x (lane (r,q) step s: x[b=s*32+8q+e][col=mt*16+r], e=0..7 —
// quarter-wave-coalesced 64B lines) and Dekker-split in-register; B from
// prepped Sbt hi/lo. 3 MFMAs/step => fp32-equivalent. Epilogue contracts with
// fp32 W; unique (i,j) writer per half-wave. first!=0: blog = val.
// ---------------------------------------------------------------------------
__global__ __launch_bounds__(256)
void gemm_bupd_kernel(const float* __restrict__ x,
                      const ushort_t* __restrict__ Sbt_hi, const ushort_t* __restrict__ Sbt_lo,
                      const float* __restrict__ W, float* __restrict__ blog,
                      const int first)
{
    int wv   = blockIdx.x * 4 + (threadIdx.x >> 6);   // 0..5759
    int lane = threadIdx.x & 63;
    int mt = wv / J_;                                 // 0..575
    int j  = wv - mt * J_;
    int r = lane & 15, q = lane >> 4;
    const float* xp = x + (size_t)(8 * q) * K_ + (mt * 16 + r);   // + (s*32+e)*K_
    size_t boff = (size_t)(j * 16 + r) * B_ + 8 * q;
    floatx4 acc = {0.f, 0.f, 0.f, 0.f};
    #pragma unroll
    for (int s = 0; s < B_ / 32; ++s) {
        bf16x8 ah, al;
        #pragma unroll
        for (int e = 0; e < 8; ++e) {
            float v = xp[(size_t)(s * 32 + e) * K_];
            __bf16 h = (__bf16)v;
            ah[e] = h;
            al[e] = (__bf16)(v - (float)h);
        }
        bf16x8 bh = *(const bf16x8*)(Sbt_hi + boff + s * 32);
        bf16x8 bl = *(const bf16x8*)(Sbt_lo + boff + s * 32);
        acc = __builtin_amdgcn_mfma_f32_16x16x32_bf16(ah, bh, acc, 0, 0, 0);
        acc = __builtin_amdgcn_mfma_f32_16x16x32_bf16(al, bh, acc, 0, 0, 0);
        acc = __builtin_amdgcn_mfma_f32_16x16x32_bf16(ah, bl, acc, 0, 0, 0);
    }
    // rows q*4+reg -> i = mt*2 + (q>>1), d = (q&1)*4 + reg; col -> o = lane&15
    int i  = mt * 2 + (q >> 1);
    int d0 = (q & 1) * 4;
    int o  = lane & 15;
    const float4 w4 = *(const float4*)(W + ((((size_t)i * J_ + j) * DOUT_ + o) * DIN_ + d0));
    float val = acc[0] * w4.x + acc[1] * w4.y + acc[2] * w4.z + acc[3] * w4.w;
    #pragma unroll
    for (int off = 1; off < 32; off <<= 1)
        val += __shfl_xor(val, off, 32);
    if ((lane & 31) == 0) {
        float* dst = blog + (size_t)(mt * 2 + (lane >> 5)) * J_ + j;
        if (first) *dst = val; else *dst += val;      // unique writer
    }
}

// ---------------------------------------------------------------------------
extern "C" void kernel_launch(void* const* d_in, const int* in_sizes, int n_in,
                              void* d_out, int out_size, void* d_ws, size_t ws_size,
                              hipStream_t stream)
{
    const float* x = (const float*)d_in[0];   // [B, I, DIN]
    const float* W = (const float*)d_in[1];   // [I, J, DOUT, DIN]
    float* s_out = (float*)d_out;             // [B, J, DOUT]

    char* ws = (char*)d_ws;
    ushort_t* Sbt_hi = (ushort_t*)(ws);                    // 81,920 B
    ushort_t* Sbt_lo = (ushort_t*)(ws + 81920);            // 81,920 B
    float*    blog   = (float*)   (ws + 163840);           // 46,080 B  (~210 KB)

    for (int it = 0; it < 3; ++it) {
        gemm_s_fused_kernel<<<160, 1024, 0, stream>>>(x, W, blog, s_out,
                                                      Sbt_hi, Sbt_lo, it);
        if (it < 2)
            gemm_bupd_kernel<<<1440, 256, 0, stream>>>(x, Sbt_hi, Sbt_lo,
                                                       W, blog, it == 0 ? 1 : 0);
    }
}